// Round 7
// baseline (249.868 us; speedup 1.0000x reference)
//
#include <hip/hip_runtime.h>
#include <hip/hip_bf16.h>

#define BB 8
#define SS 2048
#define DD 384
#define HH 8
#define HD 48
#define QT 32
#define KT 32

typedef unsigned short u16;
typedef unsigned int u32;
typedef unsigned short u16x4 __attribute__((ext_vector_type(4)));
typedef unsigned short u16x8 __attribute__((ext_vector_type(8)));
typedef short s16x8 __attribute__((ext_vector_type(8)));
typedef float f32x4 __attribute__((ext_vector_type(4)));

__device__ __forceinline__ float bf2f(u16 v){
  union { u32 u; float f; } x; x.u = ((u32)v) << 16; return x.f;
}
__device__ __forceinline__ u16 f2bf(float f){
  union { float f; u32 u; } x; x.f = f;
  u32 r = x.u + 0x7fffu + ((x.u >> 16) & 1u);
  return (u16)(r >> 16);
}
// split fp32 into hi (truncated bf16) + lo (bf16 of residual); hi+lo ~ 17-bit mantissa
__device__ __forceinline__ void split2(float f, u16& h, u16& l){
  union { float f; u32 u; } x; x.f = f;
  h = (u16)(x.u >> 16);
  l = f2bf(f - bf2f(h));
}
// pack two f32 -> two truncated bf16 in one u32 (lo = a, hi = b)
__device__ __forceinline__ u32 pack_trunc2(float a, float b){
  union { float f; u32 u; } xa, xb; xa.f = a; xb.f = b;
  return (xa.u >> 16) | (xb.u & 0xffff0000u);
}

// lgkm-only barrier: LDS writes visible, but global loads stay in flight
#define LBAR() do { \
  asm volatile("s_waitcnt lgkmcnt(0)" ::: "memory"); \
  __builtin_amdgcn_s_barrier(); \
  asm volatile("" ::: "memory"); \
} while (0)

// ---------------- Kernel 1: QKV projection, split-bf16 MFMA GEMM ----------------
// C[16384 x 1152] = x[16384 x 384] * Wqkv^T ; scatter to Q (pre-scaled by
// log2(e)/sqrt(48) so attn softmax can use exp2), K ([B,H,S,48]) and
// V^T ([B,H,48,S]) bf16 with bias.
__global__ __launch_bounds__(512, 4) void qkv_gemm(
    const float* __restrict__ x, const float* __restrict__ W,
    const float* __restrict__ bias,
    u16* __restrict__ Q, u16* __restrict__ Kd, u16* __restrict__ Vt)
{
  __shared__ u16 Ah[128][40], Al[128][40], Bh[128][40], Bl[128][40];
  const int tid  = threadIdx.x;
  const int w    = tid >> 6, lane = tid & 63;
  const int lg   = lane >> 4, ln = lane & 15;
  const int wm   = w >> 1, wn = w & 1;
  const int mb   = blockIdx.x / 9, nb = blockIdx.x % 9;
  const int m0   = mb * 128, n0 = nb * 128;
  const int srow = tid >> 3, sk4 = (tid & 7) << 2;
  const float qscale = 0.2082350972f;  // log2(e)/sqrt(48)

  f32x4 acc[8];
  #pragma unroll
  for (int i = 0; i < 8; i++) acc[i] = (f32x4){0.f,0.f,0.f,0.f};

  for (int ks = 0; ks < 12; ks++){
    const int k0 = ks * 32;
    __syncthreads();
    #pragma unroll
    for (int p = 0; p < 2; p++){
      const int row = srow + p*64;
      float4 av = *(const float4*)(x + (long)(m0+row)*DD + k0 + sk4);
      float4 bv = *(const float4*)(W + (long)(n0+row)*DD + k0 + sk4);
      u16 h0,l0,h1,l1,h2,l2,h3,l3;
      split2(av.x,h0,l0); split2(av.y,h1,l1); split2(av.z,h2,l2); split2(av.w,h3,l3);
      *(u16x4*)&Ah[row][sk4] = (u16x4){h0,h1,h2,h3};
      *(u16x4*)&Al[row][sk4] = (u16x4){l0,l1,l2,l3};
      split2(bv.x,h0,l0); split2(bv.y,h1,l1); split2(bv.z,h2,l2); split2(bv.w,h3,l3);
      *(u16x4*)&Bh[row][sk4] = (u16x4){h0,h1,h2,h3};
      *(u16x4*)&Bl[row][sk4] = (u16x4){l0,l1,l2,l3};
    }
    __syncthreads();
    s16x8 bh[4], bl[4];
    #pragma unroll
    for (int fn = 0; fn < 4; fn++){
      const int br = wn*64 + fn*16 + ln;
      bh[fn] = *(const s16x8*)&Bh[br][lg*8];
      bl[fn] = *(const s16x8*)&Bl[br][lg*8];
    }
    #pragma unroll
    for (int fm = 0; fm < 2; fm++){
      const int ar = wm*32 + fm*16 + ln;
      s16x8 ah = *(const s16x8*)&Ah[ar][lg*8];
      s16x8 al = *(const s16x8*)&Al[ar][lg*8];
      #pragma unroll
      for (int fn = 0; fn < 4; fn++){
        f32x4 c = acc[fm*4+fn];
        c = __builtin_amdgcn_mfma_f32_16x16x32_bf16(ah, bh[fn], c, 0, 0, 0);
        c = __builtin_amdgcn_mfma_f32_16x16x32_bf16(ah, bl[fn], c, 0, 0, 0);
        c = __builtin_amdgcn_mfma_f32_16x16x32_bf16(al, bh[fn], c, 0, 0, 0);
        acc[fm*4+fn] = c;
      }
    }
  }
  // epilogue: row = lg*4+r (M=token), col = ln (N=e); scatter
  #pragma unroll
  for (int fm = 0; fm < 2; fm++){
    #pragma unroll
    for (int fn = 0; fn < 4; fn++){
      const int e = n0 + wn*64 + fn*16 + ln;
      const float bi = bias[e];
      const int h = e / 144, c = e % 144;
      #pragma unroll
      for (int r = 0; r < 4; r++){
        const int mm = m0 + wm*32 + fm*16 + lg*4 + r;
        const int bb = mm >> 11, s = mm & 2047;
        const float v = acc[fm*4+fn][r] + bi;
        if (c < 48){
          Q[(((long)(bb*HH + h))*SS + s)*HD + c] = f2bf(v * qscale);
        } else if (c < 96){
          Kd[(((long)(bb*HH + h))*SS + s)*HD + (c-48)] = f2bf(v);
        } else {
          // V transposed: [B,H,48,S]
          Vt[(((long)(bb*HH + h))*HD + (c-96))*SS + s] = f2bf(v);
        }
      }
    }
  }
}

// ---------------- Kernel 2: MFMA attention, single-barrier pipeline ----------------
// Block: one (b, 32-query tile), 8 waves = 8 heads.
// Double-buffered bf16 score (Ss) and P (Pb) buffers, parity cb = t&1.
// Region t (between barriers): PV(t-1) | softmax(t): Ss[cb]->Pb[cb] |
// QK^T(t+1) -> Ss[cb^1]. Hazards: softmax(t) reads Ss[cb] written pre-barrier;
// QK^T(t+1) writes the OTHER Ss buffer; PV(t-1) reads Pb[cb^1] while
// softmax(t) writes Pb[cb]; each buffer's WAR is separated by >=1 barrier.
__global__ __launch_bounds__(512, 4) void attn_kernel(
    const u16* __restrict__ Q, const u16* __restrict__ K,
    const u16* __restrict__ Vg, float* __restrict__ vals)
{
  __shared__ u16 Ss[2][HH][QT][36];   // bf16 scores [cb][h][q][k], 72B rows
  __shared__ u16 Pb[2][HH][QT][40];   // bf16 P [cb][h][q][k], 80B rows (b128 ok)

  const int tid  = threadIdx.x;
  const int h    = tid >> 6;
  const int lane = tid & 63;
  // XCD-chunked swizzle: 512 blocks, 8 XCDs -> XCD x gets exactly batch b=x.
  const int wg   = ((int)blockIdx.x % 8) * 64 + (int)blockIdx.x / 8;
  const int b    = wg >> 6;
  const int qt   = wg & 63;
  const int q0   = qt * QT;
  const int lg   = lane >> 4;
  const int ln   = lane & 15;

  const long hbase = ((long)(b*HH + h)) * SS;
  const u16* vbase = Vg + ((long)(b*HH + h)) * HD * SS;
  const s16x8 z8 = (s16x8){0,0,0,0,0,0,0,0};

  // Q fragments (B operand of swapped QK^T) for both subtiles, held all kernel.
  s16x8 qf0[2], qf1[2];
  #pragma unroll
  for (int qs = 0; qs < 2; qs++){
    const u16* qp = Q + (hbase + q0 + qs*16 + ln)*HD;
    qf0[qs] = *(const s16x8*)(qp + lg*8);
    if (lane < 32) qf1[qs] = *(const s16x8*)(qp + 32 + lg*8);
    else           qf1[qs] = z8;
  }

  f32x4 oacc[2][3];
  #pragma unroll
  for (int qs = 0; qs < 2; qs++)
    #pragma unroll
    for (int c = 0; c < 3; c++) oacc[qs][c] = (f32x4){0.f,0.f,0.f,0.f};

  // softmax mapping: thread owns (q = tid>>4, k = smk, smk+1)
  const int smq = tid >> 4, smk = (tid & 15) << 1;

  // QK^T for tile at key offset k0x, writing score buffer cbx
#define QKT(cbx, k0x) { \
    __builtin_amdgcn_s_setprio(1); \
    _Pragma("unroll") \
    for (int nt = 0; nt < 2; nt++){ \
      const u16* kp = K + (hbase + (k0x) + nt*16 + ln)*HD; \
      s16x8 kf0 = *(const s16x8*)(kp + lg*8); \
      s16x8 kf1; \
      if (lane < 32) kf1 = *(const s16x8*)(kp + 32 + lg*8); \
      else           kf1 = z8; \
      _Pragma("unroll") \
      for (int qs = 0; qs < 2; qs++){ \
        f32x4 a = (f32x4){0.f,0.f,0.f,0.f}; \
        a = __builtin_amdgcn_mfma_f32_16x16x32_bf16(kf0, qf0[qs], a, 0, 0, 0); \
        a = __builtin_amdgcn_mfma_f32_16x16x32_bf16(kf1, qf1[qs], a, 0, 0, 0); \
        u32 w0 = pack_trunc2(a[0], a[1]); \
        u32 w1 = pack_trunc2(a[2], a[3]); \
        u32* dst = (u32*)&Ss[cbx][h][qs*16 + ln][nt*16 + lg*4]; \
        dst[0] = w0; dst[1] = w1; \
      } \
    } \
    __builtin_amdgcn_s_setprio(0); \
  }

  // prologue: scores for tile 0 into Ss[0]
  QKT(0, 0)
  LBAR();

  int cb = 0, k0 = 0;
  for (int t = 0; t < SS/KT; t++){
    // V(t) fragments: issued now, consumed after the barrier (latency hidden
    // under QK^T(t+1) + softmax(t))
    s16x8 vf0 = *(const s16x8*)(vbase + (long)(     ln)*SS + k0 + lg*8);
    s16x8 vf1 = *(const s16x8*)(vbase + (long)(16 + ln)*SS + k0 + lg*8);
    s16x8 vf2 = *(const s16x8*)(vbase + (long)(32 + ln)*SS + k0 + lg*8);

    // QK^T for NEXT tile into the other buffer (no barrier needed: softmax
    // below reads Ss[cb], this writes Ss[cb^1])
    if (t < SS/KT - 1) QKT(cb^1, k0 + KT)

    // softmax(t): 8-head softmax for (smq, smk) and (smq, smk+1)
    {
      float e0[8], e1[8];
      float sum0 = 0.f, sum1 = 0.f;
      #pragma unroll
      for (int hh = 0; hh < 8; hh++){
        u32 wv = *(const u32*)&Ss[cb][hh][smq][smk];
        union { u32 u; float f; } a0, a1;
        a0.u = wv << 16; a1.u = wv & 0xffff0000u;
        e0[hh] = __builtin_amdgcn_exp2f(a0.f);
        e1[hh] = __builtin_amdgcn_exp2f(a1.f);
        sum0 += e0[hh]; sum1 += e1[hh];
      }
      float r0 = __builtin_amdgcn_rcpf(sum0);
      float r1 = __builtin_amdgcn_rcpf(sum1);
      #pragma unroll
      for (int hh = 0; hh < 8; hh++)
        *(u32*)&Pb[cb][hh][smq][smk] = pack_trunc2(e0[hh]*r0, e1[hh]*r1);
    }

    LBAR();   // Ss[cb^1] + Pb[cb] visible; orders all WARs one tile apart

    // PV(t): read P from Pb[cb], V from registers
    __builtin_amdgcn_s_setprio(1);
    #pragma unroll
    for (int qs = 0; qs < 2; qs++){
      s16x8 pf = *(const s16x8*)&Pb[cb][h][qs*16 + ln][lg*8];
      oacc[qs][0] = __builtin_amdgcn_mfma_f32_16x16x32_bf16(pf, vf0, oacc[qs][0], 0, 0, 0);
      oacc[qs][1] = __builtin_amdgcn_mfma_f32_16x16x32_bf16(pf, vf1, oacc[qs][1], 0, 0, 0);
      oacc[qs][2] = __builtin_amdgcn_mfma_f32_16x16x32_bf16(pf, vf2, oacc[qs][2], 0, 0, 0);
    }
    __builtin_amdgcn_s_setprio(0);

    cb ^= 1; k0 += KT;
  }
#undef QKT

  // store vals[b][h][q][d] fp32 (bug-compatible flat layout)
  float* op = vals + (hbase + q0)*HD;
  #pragma unroll
  for (int qs = 0; qs < 2; qs++)
    #pragma unroll
    for (int c = 0; c < 3; c++)
      #pragma unroll
      for (int r = 0; r < 4; r++)
        op[(long)(qs*16 + lg*4 + r)*HD + c*16 + ln] = oacc[qs][c][r];
}

// ---------------- Kernel 3: output projection, split-bf16 MFMA GEMM ----------------
__global__ __launch_bounds__(512, 4) void out_gemm(
    const float* __restrict__ A, const float* __restrict__ W,
    const float* __restrict__ bias, float* __restrict__ out)
{
  __shared__ u16 Ah[128][40], Al[128][40], Bh[128][40], Bl[128][40];
  const int tid  = threadIdx.x;
  const int w    = tid >> 6, lane = tid & 63;
  const int lg   = lane >> 4, ln = lane & 15;
  const int wm   = w >> 1, wn = w & 1;
  const int mb   = blockIdx.x / 3, nb = blockIdx.x % 3;
  const int m0   = mb * 128, n0 = nb * 128;
  const int srow = tid >> 3, sk4 = (tid & 7) << 2;

  f32x4 acc[8];
  #pragma unroll
  for (int i = 0; i < 8; i++) acc[i] = (f32x4){0.f,0.f,0.f,0.f};

  for (int ks = 0; ks < 12; ks++){
    const int k0 = ks * 32;
    __syncthreads();
    #pragma unroll
    for (int p = 0; p < 2; p++){
      const int row = srow + p*64;
      float4 av = *(const float4*)(A + (long)(m0+row)*DD + k0 + sk4);
      float4 bv = *(const float4*)(W + (long)(n0+row)*DD + k0 + sk4);
      u16 h0,l0,h1,l1,h2,l2,h3,l3;
      split2(av.x,h0,l0); split2(av.y,h1,l1); split2(av.z,h2,l2); split2(av.w,h3,l3);
      *(u16x4*)&Ah[row][sk4] = (u16x4){h0,h1,h2,h3};
      *(u16x4*)&Al[row][sk4] = (u16x4){l0,l1,l2,l3};
      split2(bv.x,h0,l0); split2(bv.y,h1,l1); split2(bv.z,h2,l2); split2(bv.w,h3,l3);
      *(u16x4*)&Bh[row][sk4] = (u16x4){h0,h1,h2,h3};
      *(u16x4*)&Bl[row][sk4] = (u16x4){l0,l1,l2,l3};
    }
    __syncthreads();
    s16x8 bh[4], bl[4];
    #pragma unroll
    for (int fn = 0; fn < 4; fn++){
      const int br = wn*64 + fn*16 + ln;
      bh[fn] = *(const s16x8*)&Bh[br][lg*8];
      bl[fn] = *(const s16x8*)&Bl[br][lg*8];
    }
    #pragma unroll
    for (int fm = 0; fm < 2; fm++){
      const int ar = wm*32 + fm*16 + ln;
      s16x8 ah = *(const s16x8*)&Ah[ar][lg*8];
      s16x8 al = *(const s16x8*)&Al[ar][lg*8];
      #pragma unroll
      for (int fn = 0; fn < 4; fn++){
        f32x4 c = acc[fm*4+fn];
        c = __builtin_amdgcn_mfma_f32_16x16x32_bf16(ah, bh[fn], c, 0, 0, 0);
        c = __builtin_amdgcn_mfma_f32_16x16x32_bf16(ah, bl[fn], c, 0, 0, 0);
        c = __builtin_amdgcn_mfma_f32_16x16x32_bf16(al, bh[fn], c, 0, 0, 0);
        acc[fm*4+fn] = c;
      }
    }
  }
  #pragma unroll
  for (int fm = 0; fm < 2; fm++){
    #pragma unroll
    for (int fn = 0; fn < 4; fn++){
      const int e = n0 + wn*64 + fn*16 + ln;
      const float bi = bias[e];
      #pragma unroll
      for (int r = 0; r < 4; r++){
        const int mm = m0 + wm*32 + fm*16 + lg*4 + r;
        out[(long)mm*DD + e] = acc[fm*4+fn][r] + bi;
      }
    }
  }
}

extern "C" void kernel_launch(void* const* d_in, const int* in_sizes, int n_in,
                              void* d_out, int out_size, void* d_ws, size_t ws_size,
                              hipStream_t stream)
{
  const float* x    = (const float*)d_in[0];
  const float* Wqkv = (const float*)d_in[1];
  const float* bqkv = (const float*)d_in[2];
  const float* Wo   = (const float*)d_in[3];
  const float* bo   = (const float*)d_in[4];
  float* out = (float*)d_out;

  const size_t QSZ = (size_t)BB*HH*SS*HD;   // 6,291,456 elems
  u16* Q  = (u16*)d_ws;
  u16* K  = Q + QSZ;
  u16* Vt = K + QSZ;                        // V^T [B,H,48,S]
  float* vals = (float*)(Vt + QSZ);         // fp32, 25.2 MB

  qkv_gemm<<<1152, 512, 0, stream>>>(x, Wqkv, bqkv, Q, K, Vt);
  attn_kernel<<<512, 512, 0, stream>>>(Q, K, Vt, vals);
  out_gemm<<<384, 512, 0, stream>>>(vals, Wo, bo, out);
}